// Round 8
// baseline (192.349 us; speedup 1.0000x reference)
//
#include <hip/hip_runtime.h>
#include <stdint.h>

typedef __attribute__((ext_vector_type(8))) short short8;            // 8 bf16 (MFMA A/B frag)
typedef __attribute__((ext_vector_type(4))) float f32x4;             // MFMA C/D frag
typedef __attribute__((ext_vector_type(4))) unsigned short ushort4v;

__device__ __forceinline__ unsigned short f2bf(float f) {
    unsigned int u = __float_as_uint(f);
    u = (u + 0x7FFFu + ((u >> 16) & 1u)) >> 16;  // RNE
    return (unsigned short)u;
}
__device__ __forceinline__ float bf2f(unsigned short h) {
    return __uint_as_float(((unsigned int)h) << 16);
}
__device__ __forceinline__ int cell_of(float ax, float ay) {
    int c0 = (int)floorf(ax * 4.f); c0 = min(max(c0, 0), 3);
    int c1 = (int)floorf(ay * 4.f); c1 = min(max(c1, 0), 3);
    return c0 + 4 * c1;
}

// ---------------------------------------------------------------------------
// zero_kernel: zero hist(16) + dhist(N+1) — replaces in-graph hipMemsetAsync
// ---------------------------------------------------------------------------
__global__ __launch_bounds__(256) void zero_kernel(int* __restrict__ p, int n) {
    int t = blockIdx.x * 256 + threadIdx.x;
    if (t < n) p[t] = 0;
}

// ---- device helpers for weight packing (frag-ordered), guarded -------------
template<int KIN>
__device__ __forceinline__ void pack_cell_elem(const float* __restrict__ W,
                                               unsigned short* __restrict__ pkc, int u) {
    constexpr int KCH = KIN / 8;  // 4*KIN/32
    if (u >= 16 * 4 * KCH * 512) return;           // guard: region overshoot safe
    int low9 = u & 511;
    int grp  = u >> 9;
    int kc = grp % KCH; grp /= KCH;
    int c  = grp & 3;
    int cell = grp >> 2;
    int lane = low9 >> 3, j = low9 & 7;
    int k = kc * 32 + (lane >> 4) * 8 + j;
    int t = k / KIN, i = k % KIN;
    int k0 = (cell & 3) + (t & 1);   if (k0 > 4) k0 = 4;
    int k1 = (cell >> 2) + (t >> 1); if (k1 > 4) k1 = 4;
    float val = W[((size_t)(k0 + 5 * k1) * KIN + i) * 64 + (c * 16 + (lane & 15))];
    pkc[u] = f2bf(val);
}

template<int KIN>
__device__ __forceinline__ void pack_root_elem(const float* __restrict__ root,
                                               unsigned short* __restrict__ pkr, int u) {
    constexpr int KCHr = KIN / 32;
    if (u >= 4 * KCHr * 512) return;               // guard: region overshoot safe
    int low9 = u & 511;
    int grp  = u >> 9;               // c*KCHr + kc
    int lane = low9 >> 3, j = low9 & 7;
    int kc = grp % KCHr, c = grp / KCHr;
    int k = kc * 32 + (lane >> 4) * 8 + j;
    int o = c * 16 + (lane & 15);
    float v = root[(size_t)k * 64 + o];
    unsigned short h = f2bf(v);
    pkr[(size_t)(grp * 2) * 512 + low9]     = h;
    pkr[(size_t)(grp * 2 + 1) * 512 + low9] = f2bf(v - bf2f(h));
}

// ---------------------------------------------------------------------------
// prep_kernel: block-region dispatch of all independent prep work:
//  [0,EB)  : hist (cell counts via ballot + per-dst counts via atomic)
//  +512    : pack cell W1   +1024 : pack cell W2
//  +8      : pack root1     +16   : pack root2
//  +CB     : x -> bf16 convert (float4-wide)
// ---------------------------------------------------------------------------
__global__ __launch_bounds__(256) void prep_kernel(
    const float* __restrict__ attr, const int* __restrict__ dst,
    int* __restrict__ hist, int* __restrict__ dhist, int E,
    const float* __restrict__ W1, const float* __restrict__ W2,
    const float* __restrict__ root1, const float* __restrict__ root2,
    unsigned short* __restrict__ pkc1, unsigned short* __restrict__ pkc2,
    unsigned short* __restrict__ pkr1, unsigned short* __restrict__ pkr2,
    const float* __restrict__ x, unsigned short* __restrict__ xb, int n4,
    int EB)
{
    __shared__ int wcnt[4][16];
    int b = blockIdx.x;
    if (b < EB) {
        int e = b * 256 + threadIdx.x;
        int lane = threadIdx.x & 63, wave = threadIdx.x >> 6;
        int cell = -1;
        if (e < E) {
            float2 a = reinterpret_cast<const float2*>(attr)[e];
            cell = cell_of(a.x, a.y);
            atomicAdd(&dhist[dst[e]], 1);
        }
        #pragma unroll
        for (int c = 0; c < 16; c++) {
            unsigned long long m = __ballot(cell == c);
            if (lane == 0) wcnt[wave][c] = __popcll(m);
        }
        __syncthreads();
        if (threadIdx.x < 16) {
            int c = threadIdx.x;
            int tot = wcnt[0][c] + wcnt[1][c] + wcnt[2][c] + wcnt[3][c];
            if (tot) atomicAdd(&hist[c], tot);
        }
        return;
    }
    b -= EB;
    if (b < 512)  { pack_cell_elem<32>(W1, pkc1, b * 256 + threadIdx.x); return; }
    b -= 512;
    if (b < 1024) { pack_cell_elem<64>(W2, pkc2, b * 256 + threadIdx.x); return; }
    b -= 1024;
    if (b < 8)    { pack_root_elem<32>(root1, pkr1, b * 256 + threadIdx.x); return; }
    b -= 8;
    if (b < 16)   { pack_root_elem<64>(root2, pkr2, b * 256 + threadIdx.x); return; }
    b -= 16;
    {
        int t = b * 256 + threadIdx.x;
        if (t < n4) {
            float4 v = reinterpret_cast<const float4*>(x)[t];
            ushort4v o = { f2bf(v.x), f2bf(v.y), f2bf(v.z), f2bf(v.w) };
            reinterpret_cast<ushort4v*>(xb)[t] = o;
        }
    }
}

// ---------------------------------------------------------------------------
// scanA: per-block (1024-wide) exclusive scan of dhist -> nof, block sums -> bsum
// Global exclusive prefix of i is nof[i] + bbase[i>>10] (fix-up fused in consumers).
// ---------------------------------------------------------------------------
__global__ __launch_bounds__(1024) void scanA_kernel(const int* __restrict__ dhist,
                                                     int* __restrict__ nof,
                                                     int* __restrict__ bsum, int Np1) {
    __shared__ int wsum[16];
    int tid = threadIdx.x, lane = tid & 63, w = tid >> 6;
    int i = blockIdx.x * 1024 + tid;
    int v = (i < Np1) ? dhist[i] : 0;
    int s = v;
    #pragma unroll
    for (int off = 1; off < 64; off <<= 1) {
        int t = __shfl_up(s, off);
        if (lane >= off) s += t;
    }
    if (lane == 63) wsum[w] = s;
    __syncthreads();
    if (tid == 0) {
        int a = 0;
        #pragma unroll
        for (int k = 0; k < 16; k++) { int t = wsum[k]; wsum[k] = a; a += t; }
        bsum[blockIdx.x] = a;
    }
    __syncthreads();
    if (i < Np1) nof[i] = wsum[w] + s - v;
}

// ---------------------------------------------------------------------------
// scan_small: (a) 16-cell exclusive scan -> off_e/off_b/cursor
//             (b) exclusive scan of NB block sums -> bbase
// ---------------------------------------------------------------------------
__global__ void scan_small_kernel(const int* __restrict__ hist, int* __restrict__ off_e,
                                  int* __restrict__ off_b, int* __restrict__ cursor,
                                  const int* __restrict__ bsum, int* __restrict__ bbase, int NB) {
    if (threadIdx.x == 0 && blockIdx.x == 0) {
        int se = 0, sb = 0;
        for (int c = 0; c < 16; c++) {
            off_e[c] = se; off_b[c] = sb; cursor[c] = se;
            se += hist[c]; sb += (hist[c] + 63) >> 6;
        }
        off_e[16] = se; off_b[16] = sb;
        int a = 0;
        for (int bks = 0; bks < NB; bks++) { int t = bsum[bks]; bbase[bks] = a; a += t; }
    }
}

// ---------------------------------------------------------------------------
// scatter: cell-bucket (ballot-ranked); writes packed per-slot edge meta
//   emeta[slot] = {src, dstpos, ax_bits, ay_bits}
// Per-dst rank via atomicSub on dhist (dead after scanA; ends at 0).
// ---------------------------------------------------------------------------
__global__ __launch_bounds__(256) void scatter_kernel(const float* __restrict__ attr,
                                                      const int* __restrict__ src,
                                                      const int* __restrict__ dst,
                                                      const int* __restrict__ nof,
                                                      const int* __restrict__ bbase,
                                                      int4* __restrict__ emeta,
                                                      int* __restrict__ cursor,
                                                      int* __restrict__ dhist, int E) {
    __shared__ int wcnt[4][16];
    __shared__ int wbase[4][16];
    int e = blockIdx.x * 256 + threadIdx.x;
    int lane = threadIdx.x & 63, wave = threadIdx.x >> 6;
    int cell = -1;
    float2 a = {0.f, 0.f};
    int mp = 0, sv = 0;
    if (e < E) {
        a = reinterpret_cast<const float2*>(attr)[e];
        cell = cell_of(a.x, a.y);
        int d = dst[e];
        int rank = atomicSub(&dhist[d], 1) - 1;      // count-1 .. 0 (permutation)
        mp = nof[d] + bbase[d >> 10] + rank;
        sv = src[e];
    }
    int myrank = 0;
    #pragma unroll
    for (int c = 0; c < 16; c++) {
        unsigned long long m = __ballot(cell == c);
        if (cell == c) myrank = __popcll(m & ((1ull << lane) - 1ull));
        if (lane == 0) wcnt[wave][c] = __popcll(m);
    }
    __syncthreads();
    if (threadIdx.x < 16) {
        int c = threadIdx.x;
        int t0 = wcnt[0][c], t1 = wcnt[1][c], t2 = wcnt[2][c], t3 = wcnt[3][c];
        int tot = t0 + t1 + t2 + t3;
        int g = tot ? atomicAdd(&cursor[c], tot) : 0;
        wbase[0][c] = g;
        wbase[1][c] = g + t0;
        wbase[2][c] = g + t0 + t1;
        wbase[3][c] = g + t0 + t1 + t2;
    }
    __syncthreads();
    if (e < E) {
        int slot = wbase[wave][cell] + myrank;
        emeta[slot] = make_int4(sv, mp, __float_as_int(a.x), __float_as_int(a.y));
    }
}

// ---------------------------------------------------------------------------
// layer_kernel: block-region merge of root GEMM + cell-bucketed edge GEMM.
//  [0, RG)   : rt[n,:] = x @ (root_hi+root_lo) + bias
//  [RG, ...) : per 16-edge tile G[t] = X[src] @ W[k_t(cell)];
//              msg[dstpos[e]] = bf16( sum_t w_t(e) * G[t] )
// NO LDS, NO barrier: B-frags read directly from pkc (per-cell slice is
// L1-sized 16/32KB, L2-resident 0.5/1MB total); waves fully independent.
// ---------------------------------------------------------------------------
template<int KIN>
__global__ __launch_bounds__(256) void layer_kernel(
    const unsigned short* __restrict__ Xb,
    const unsigned short* __restrict__ pkr, float* __restrict__ rt,
    const float* __restrict__ bias, int N, int RG,
    const unsigned short* __restrict__ pkc, unsigned short* __restrict__ msg,
    const int4* __restrict__ emeta,
    const int* __restrict__ off_e, const int* __restrict__ off_b)
{
    constexpr int KCHr = KIN / 32;
    constexpr int KCH  = 4 * KCHr;

    const int lane = threadIdx.x & 63;
    const int wave = threadIdx.x >> 6;
    const int lrow = lane & 15, lch = lane >> 4;

    if (blockIdx.x < RG) {
        // ---- root GEMM ----
        const int mbase = blockIdx.x * 64 + wave * 16;
        short8 afrag[KCHr];
        {
            int row = mbase + lrow;
            if (row > N - 1) row = N - 1;
            const unsigned short* ap = Xb + (size_t)row * KIN + lch * 8;
            #pragma unroll
            for (int kc = 0; kc < KCHr; kc++)
                afrag[kc] = *reinterpret_cast<const short8*>(ap + kc * 32);
        }
        f32x4 acc[4];
        #pragma unroll
        for (int c = 0; c < 4; c++) acc[c] = (f32x4){0.f, 0.f, 0.f, 0.f};
        #pragma unroll
        for (int c = 0; c < 4; c++) {
            #pragma unroll
            for (int kc = 0; kc < KCHr; kc++) {
                short8 bh = *reinterpret_cast<const short8*>(pkr + ((size_t)(c * KCHr + kc) * 2    ) * 512 + lane * 8);
                short8 bl = *reinterpret_cast<const short8*>(pkr + ((size_t)(c * KCHr + kc) * 2 + 1) * 512 + lane * 8);
                acc[c] = __builtin_amdgcn_mfma_f32_16x16x32_bf16(afrag[kc], bh, acc[c], 0, 0, 0);
                acc[c] = __builtin_amdgcn_mfma_f32_16x16x32_bf16(afrag[kc], bl, acc[c], 0, 0, 0);
            }
        }
        #pragma unroll
        for (int c = 0; c < 4; c++) {
            int o = c * 16 + lrow;
            float bv = bias[o];
            #pragma unroll
            for (int r = 0; r < 4; r++) {
                int m = mbase + lch * 4 + r;
                if (m < N) rt[(size_t)m * 64 + o] = acc[c][r] + bv;
            }
        }
        return;
    }

    // ---- edge GEMM ----
    const int b = blockIdx.x - RG;
    if (b >= off_b[16]) return;
    int cell = 0;
    #pragma unroll
    for (int c = 1; c < 16; c++) cell += (b >= off_b[c]);
    const int tile = b - off_b[cell];

    const int ebeg = off_e[cell];
    const int eend = off_e[cell + 1];
    const int eslot = ebeg + (tile * 4 + wave) * 16 + lrow;
    const bool valid = eslot < eend;

    const int4 em = emeta[valid ? eslot : ebeg];
    const int s = em.x;
    const int mp = valid ? em.y : -1;
    const float ax = __int_as_float(em.z);
    const float ay = __int_as_float(em.w);

    const float f0 = ax * 4.f - (float)(cell & 3);
    const float f1 = ay * 4.f - (float)(cell >> 2);
    float w[4] = { (1.f - f0) * (1.f - f1), f0 * (1.f - f1),
                   (1.f - f0) * f1,         f0 * f1 };

    short8 xfrag[KCHr];
    {
        const unsigned short* xp = Xb + (size_t)s * KIN + lch * 8;
        #pragma unroll
        for (int kcr = 0; kcr < KCHr; kcr++)
            xfrag[kcr] = *reinterpret_cast<const short8*>(xp + kcr * 32);
    }

    // per-row basis weights + msg position (D layout: row = lch*4+r)
    float wr[4][4];
    int pv[4];
    #pragma unroll
    for (int r = 0; r < 4; r++) {
        int er = lch * 4 + r;
        #pragma unroll
        for (int t = 0; t < 4; t++) wr[t][r] = __shfl(w[t], er);
        pv[r] = __shfl(mp, er);
    }

    const unsigned short* Bp = pkc + (size_t)cell * (4 * KCH * 512) + lane * 8;

    #pragma unroll
    for (int ch = 0; ch < 2; ch++) {
        f32x4 accT[4][2];  // [t][c2]
        #pragma unroll
        for (int t = 0; t < 4; t++)
            #pragma unroll
            for (int c2 = 0; c2 < 2; c2++)
                accT[t][c2] = (f32x4){0.f, 0.f, 0.f, 0.f};

        #pragma unroll
        for (int t = 0; t < 4; t++) {
            #pragma unroll
            for (int kcr = 0; kcr < KCHr; kcr++) {
                #pragma unroll
                for (int c2 = 0; c2 < 2; c2++) {
                    int c = ch * 2 + c2;
                    short8 bf = *reinterpret_cast<const short8*>(
                        Bp + (size_t)((c * KCH) + (t * KCHr + kcr)) * 512);
                    accT[t][c2] = __builtin_amdgcn_mfma_f32_16x16x32_bf16(xfrag[kcr], bf, accT[t][c2], 0, 0, 0);
                }
            }
        }

        #pragma unroll
        for (int c2 = 0; c2 < 2; c2++) {
            const int o = (ch * 2 + c2) * 16 + lrow;
            #pragma unroll
            for (int r = 0; r < 4; r++) {
                if (pv[r] >= 0) {
                    float m = wr[0][r] * accT[0][c2][r] + wr[1][r] * accT[1][c2][r]
                            + wr[2][r] * accT[2][c2][r] + wr[3][r] * accT[3][c2][r];
                    msg[(size_t)pv[r] * 64 + o] = f2bf(m);
                }
            }
        }
    }
}

// ---------------------------------------------------------------------------
// Segment-sum (dst-sorted bf16 msg rows contiguous per node) + root part.
// MODE 0: h = bf16(relu(rt + sum))      MODE 1: out = relu(rt+sum) @ fcw + fcb
// ---------------------------------------------------------------------------
template<int MODE>
__global__ __launch_bounds__(256) void segsum_kernel(
    const unsigned short* __restrict__ msg, const float* __restrict__ rt,
    const int* __restrict__ nof, const int* __restrict__ bbase,
    unsigned short* __restrict__ hout,
    const float* __restrict__ fcw, const float* __restrict__ fcb,
    float* __restrict__ out, int N)
{
    int n = blockIdx.x * 4 + (threadIdx.x >> 6);
    if (n >= N) return;
    int lane = threadIdx.x & 63;
    float acc = rt[(size_t)n * 64 + lane];
    int jb = nof[n]     + bbase[n >> 10];
    int je = nof[n + 1] + bbase[(n + 1) >> 10];
    int j = jb;
    for (; j + 3 < je; j += 4) {
        float a0 = bf2f(msg[(size_t)(j + 0) * 64 + lane]);
        float a1 = bf2f(msg[(size_t)(j + 1) * 64 + lane]);
        float a2 = bf2f(msg[(size_t)(j + 2) * 64 + lane]);
        float a3 = bf2f(msg[(size_t)(j + 3) * 64 + lane]);
        acc += a0; acc += a1; acc += a2; acc += a3;
    }
    for (; j < je; j++) acc += bf2f(msg[(size_t)j * 64 + lane]);
    acc = fmaxf(acc, 0.f);
    if (MODE == 0) {
        hout[(size_t)n * 64 + lane] = f2bf(acc);
    } else {
        float p0 = acc * fcw[lane * 3 + 0];
        float p1 = acc * fcw[lane * 3 + 1];
        float p2 = acc * fcw[lane * 3 + 2];
        #pragma unroll
        for (int off = 32; off; off >>= 1) {
            p0 += __shfl_xor(p0, off);
            p1 += __shfl_xor(p1, off);
            p2 += __shfl_xor(p2, off);
        }
        if (lane == 0) {
            out[(size_t)n * 3 + 0] = p0 + fcb[0];
            out[(size_t)n * 3 + 1] = p1 + fcb[1];
            out[(size_t)n * 3 + 2] = p2 + fcb[2];
        }
    }
}

// ---------------------------------------------------------------------------
extern "C" void kernel_launch(void* const* d_in, const int* in_sizes, int n_in,
                              void* d_out, int out_size, void* d_ws, size_t ws_size,
                              hipStream_t stream)
{
    const float* x     = (const float*)d_in[0];
    const int*   ei    = (const int*)  d_in[1];
    const float* attr  = (const float*)d_in[2];
    const float* W1    = (const float*)d_in[3];
    const float* root1 = (const float*)d_in[4];
    const float* b1    = (const float*)d_in[5];
    const float* W2    = (const float*)d_in[6];
    const float* root2 = (const float*)d_in[7];
    const float* b2    = (const float*)d_in[8];
    const float* fcw   = (const float*)d_in[9];
    const float* fcb   = (const float*)d_in[10];

    const int N = in_sizes[0] / 32;
    const int E = in_sizes[1] / 2;
    const int* srcp = ei;
    const int* dstp = ei + E;

    char* wsp = (char*)d_ws;
    auto alloc = [&](size_t bytes) -> char* {
        char* p = wsp;
        wsp += (bytes + 255) & ~(size_t)255;
        return p;
    };
    const int NB = (N + 1 + 1023) / 1024;   // scanA blocks

    float*          rt       = (float*)alloc((size_t)N * 64 * 4);
    unsigned short* xb       = (unsigned short*)alloc((size_t)N * 32 * 2);
    unsigned short* h1b      = (unsigned short*)alloc((size_t)N * 64 * 2);
    unsigned short* pkr1     = (unsigned short*)alloc((size_t)4 * 1 * 2 * 512 * 2);
    unsigned short* pkr2     = (unsigned short*)alloc((size_t)4 * 2 * 2 * 512 * 2);
    unsigned short* pkc1     = (unsigned short*)alloc((size_t)16 * 4 * 4 * 512 * 2);
    unsigned short* pkc2     = (unsigned short*)alloc((size_t)16 * 4 * 8 * 512 * 2);
    int4*           emeta    = (int4*)alloc((size_t)E * 16);
    int*            nof      = (int*)alloc((size_t)(N + 1) * 4);
    int*            bsum     = (int*)alloc((size_t)NB * 4);
    int*            bbase    = (int*)alloc((size_t)NB * 4);
    int*            off_e    = (int*)alloc(17 * 4);
    int*            off_b    = (int*)alloc(17 * 4);
    int*            cursor   = (int*)alloc(16 * 4);
    // zeroed region: hist16 | dhist[N+1]
    int*            zbase    = (int*)alloc((size_t)(16 + N + 1) * 4);
    int*            hist     = zbase;
    int*            dhist    = zbase + 16;
    unsigned short* msg      = (unsigned short*)alloc((size_t)E * 64 * 2);

    const int ZN = 16 + N + 1;
    zero_kernel<<<(ZN + 255) / 256, 256, 0, stream>>>(zbase, ZN);

    const int EB = (E + 255) / 256;
    const int CB = (N * 8 + 255) / 256;              // float4 convert blocks
    const int prep_grid = EB + 512 + 1024 + 8 + 16 + CB;

    prep_kernel<<<prep_grid, 256, 0, stream>>>(attr, dstp, hist, dhist, E,
                                               W1, W2, root1, root2,
                                               pkc1, pkc2, pkr1, pkr2,
                                               x, xb, N * 8, EB);
    scanA_kernel<<<NB, 1024, 0, stream>>>(dhist, nof, bsum, N + 1);
    scan_small_kernel<<<1, 64, 0, stream>>>(hist, off_e, off_b, cursor, bsum, bbase, NB);
    scatter_kernel<<<EB, 256, 0, stream>>>(attr, srcp, dstp, nof, bbase, emeta, cursor, dhist, E);

    const int RG = (N + 63) / 64;
    const int lgrid = RG + (E + 63) / 64 + 16;
    const int sgrid = (N + 3) / 4;

    layer_kernel<32><<<lgrid, 256, 0, stream>>>(xb, pkr1, rt, b1, N, RG,
                                                pkc1, msg, emeta, off_e, off_b);
    segsum_kernel<0><<<sgrid, 256, 0, stream>>>(msg, rt, nof, bbase, h1b, fcw, fcb, (float*)d_out, N);

    layer_kernel<64><<<lgrid, 256, 0, stream>>>(h1b, pkr2, rt, b2, N, RG,
                                                pkc2, msg, emeta, off_e, off_b);
    segsum_kernel<1><<<sgrid, 256, 0, stream>>>(msg, rt, nof, bbase, nullptr, fcw, fcb, (float*)d_out, N);
}

// Round 9
// 181.417 us; speedup vs baseline: 1.0603x; 1.0603x over previous
//
#include <hip/hip_runtime.h>
#include <stdint.h>

typedef __attribute__((ext_vector_type(8))) short short8;            // 8 bf16 (MFMA A/B frag)
typedef __attribute__((ext_vector_type(4))) float f32x4;             // MFMA C/D frag
typedef __attribute__((ext_vector_type(4))) unsigned short ushort4v;

#define CHUNK 512   // edges per edge-block (8 tiles x 4 waves x 16 edges)

__device__ __forceinline__ unsigned short f2bf(float f) {
    unsigned int u = __float_as_uint(f);
    u = (u + 0x7FFFu + ((u >> 16) & 1u)) >> 16;  // RNE
    return (unsigned short)u;
}
__device__ __forceinline__ float bf2f(unsigned short h) {
    return __uint_as_float(((unsigned int)h) << 16);
}
__device__ __forceinline__ int cell_of(float ax, float ay) {
    int c0 = (int)floorf(ax * 4.f); c0 = min(max(c0, 0), 3);
    int c1 = (int)floorf(ay * 4.f); c1 = min(max(c1, 0), 3);
    return c0 + 4 * c1;
}

// ---------------------------------------------------------------------------
// zero_kernel: zero hist(16) + dhist(N+1) — replaces in-graph hipMemsetAsync
// ---------------------------------------------------------------------------
__global__ __launch_bounds__(256) void zero_kernel(int* __restrict__ p, int n) {
    int t = blockIdx.x * 256 + threadIdx.x;
    if (t < n) p[t] = 0;
}

// ---- device helpers for weight packing (frag-ordered), guarded -------------
template<int KIN>
__device__ __forceinline__ void pack_cell_elem(const float* __restrict__ W,
                                               unsigned short* __restrict__ pkc, int u) {
    constexpr int KCH = KIN / 8;  // 4*KIN/32
    if (u >= 16 * 4 * KCH * 512) return;           // guard: region overshoot safe
    int low9 = u & 511;
    int grp  = u >> 9;
    int kc = grp % KCH; grp /= KCH;
    int c  = grp & 3;
    int cell = grp >> 2;
    int lane = low9 >> 3, j = low9 & 7;
    int k = kc * 32 + (lane >> 4) * 8 + j;
    int t = k / KIN, i = k % KIN;
    int k0 = (cell & 3) + (t & 1);   if (k0 > 4) k0 = 4;
    int k1 = (cell >> 2) + (t >> 1); if (k1 > 4) k1 = 4;
    float val = W[((size_t)(k0 + 5 * k1) * KIN + i) * 64 + (c * 16 + (lane & 15))];
    pkc[u] = f2bf(val);
}

template<int KIN>
__device__ __forceinline__ void pack_root_elem(const float* __restrict__ root,
                                               unsigned short* __restrict__ pkr, int u) {
    constexpr int KCHr = KIN / 32;
    if (u >= 4 * KCHr * 512) return;               // guard: region overshoot safe
    int low9 = u & 511;
    int grp  = u >> 9;               // c*KCHr + kc
    int lane = low9 >> 3, j = low9 & 7;
    int kc = grp % KCHr, c = grp / KCHr;
    int k = kc * 32 + (lane >> 4) * 8 + j;
    int o = c * 16 + (lane & 15);
    float v = root[(size_t)k * 64 + o];
    unsigned short h = f2bf(v);
    pkr[(size_t)(grp * 2) * 512 + low9]     = h;
    pkr[(size_t)(grp * 2 + 1) * 512 + low9] = f2bf(v - bf2f(h));
}

// ---------------------------------------------------------------------------
// prep_kernel: block-region dispatch of all independent prep work:
//  [0,EB)  : hist (cell counts via ballot + per-dst counts via atomic)
//  +512    : pack cell W1   +1024 : pack cell W2
//  +8      : pack root1     +16   : pack root2
//  +CB     : x -> bf16 convert (float4-wide)
// ---------------------------------------------------------------------------
__global__ __launch_bounds__(256) void prep_kernel(
    const float* __restrict__ attr, const int* __restrict__ dst,
    int* __restrict__ hist, int* __restrict__ dhist, int E,
    const float* __restrict__ W1, const float* __restrict__ W2,
    const float* __restrict__ root1, const float* __restrict__ root2,
    unsigned short* __restrict__ pkc1, unsigned short* __restrict__ pkc2,
    unsigned short* __restrict__ pkr1, unsigned short* __restrict__ pkr2,
    const float* __restrict__ x, unsigned short* __restrict__ xb, int n4,
    int EB)
{
    __shared__ int wcnt[4][16];
    int b = blockIdx.x;
    if (b < EB) {
        int e = b * 256 + threadIdx.x;
        int lane = threadIdx.x & 63, wave = threadIdx.x >> 6;
        int cell = -1;
        if (e < E) {
            float2 a = reinterpret_cast<const float2*>(attr)[e];
            cell = cell_of(a.x, a.y);
            atomicAdd(&dhist[dst[e]], 1);
        }
        #pragma unroll
        for (int c = 0; c < 16; c++) {
            unsigned long long m = __ballot(cell == c);
            if (lane == 0) wcnt[wave][c] = __popcll(m);
        }
        __syncthreads();
        if (threadIdx.x < 16) {
            int c = threadIdx.x;
            int tot = wcnt[0][c] + wcnt[1][c] + wcnt[2][c] + wcnt[3][c];
            if (tot) atomicAdd(&hist[c], tot);
        }
        return;
    }
    b -= EB;
    if (b < 512)  { pack_cell_elem<32>(W1, pkc1, b * 256 + threadIdx.x); return; }
    b -= 512;
    if (b < 1024) { pack_cell_elem<64>(W2, pkc2, b * 256 + threadIdx.x); return; }
    b -= 1024;
    if (b < 8)    { pack_root_elem<32>(root1, pkr1, b * 256 + threadIdx.x); return; }
    b -= 8;
    if (b < 16)   { pack_root_elem<64>(root2, pkr2, b * 256 + threadIdx.x); return; }
    b -= 16;
    {
        int t = b * 256 + threadIdx.x;
        if (t < n4) {
            float4 v = reinterpret_cast<const float4*>(x)[t];
            ushort4v o = { f2bf(v.x), f2bf(v.y), f2bf(v.z), f2bf(v.w) };
            reinterpret_cast<ushort4v*>(xb)[t] = o;
        }
    }
}

// ---------------------------------------------------------------------------
// scanA: per-block (1024-wide) exclusive scan of dhist -> nof, block sums -> bsum
// Global exclusive prefix of i is nof[i] + bbase[i>>10] (fix-up fused in consumers).
// ---------------------------------------------------------------------------
__global__ __launch_bounds__(1024) void scanA_kernel(const int* __restrict__ dhist,
                                                     int* __restrict__ nof,
                                                     int* __restrict__ bsum, int Np1) {
    __shared__ int wsum[16];
    int tid = threadIdx.x, lane = tid & 63, w = tid >> 6;
    int i = blockIdx.x * 1024 + tid;
    int v = (i < Np1) ? dhist[i] : 0;
    int s = v;
    #pragma unroll
    for (int off = 1; off < 64; off <<= 1) {
        int t = __shfl_up(s, off);
        if (lane >= off) s += t;
    }
    if (lane == 63) wsum[w] = s;
    __syncthreads();
    if (tid == 0) {
        int a = 0;
        #pragma unroll
        for (int k = 0; k < 16; k++) { int t = wsum[k]; wsum[k] = a; a += t; }
        bsum[blockIdx.x] = a;
    }
    __syncthreads();
    if (i < Np1) nof[i] = wsum[w] + s - v;
}

// ---------------------------------------------------------------------------
// scan_small: (a) 16-cell exclusive scan -> off_e / off_b (CHUNK-granular) / cursor
//             (b) exclusive scan of NB block sums -> bbase
// ---------------------------------------------------------------------------
__global__ void scan_small_kernel(const int* __restrict__ hist, int* __restrict__ off_e,
                                  int* __restrict__ off_b, int* __restrict__ cursor,
                                  const int* __restrict__ bsum, int* __restrict__ bbase, int NB) {
    if (threadIdx.x == 0 && blockIdx.x == 0) {
        int se = 0, sb = 0;
        for (int c = 0; c < 16; c++) {
            off_e[c] = se; off_b[c] = sb; cursor[c] = se;
            se += hist[c]; sb += (hist[c] + CHUNK - 1) / CHUNK;
        }
        off_e[16] = se; off_b[16] = sb;
        int a = 0;
        for (int bks = 0; bks < NB; bks++) { int t = bsum[bks]; bbase[bks] = a; a += t; }
    }
}

// ---------------------------------------------------------------------------
// scatter: cell-bucket (ballot-ranked); writes packed per-slot edge meta
//   emeta[slot] = {src, dstpos, ax_bits, ay_bits}
// Per-dst rank via atomicSub on dhist (dead after scanA; ends at 0).
// ---------------------------------------------------------------------------
__global__ __launch_bounds__(256) void scatter_kernel(const float* __restrict__ attr,
                                                      const int* __restrict__ src,
                                                      const int* __restrict__ dst,
                                                      const int* __restrict__ nof,
                                                      const int* __restrict__ bbase,
                                                      int4* __restrict__ emeta,
                                                      int* __restrict__ cursor,
                                                      int* __restrict__ dhist, int E) {
    __shared__ int wcnt[4][16];
    __shared__ int wbase[4][16];
    int e = blockIdx.x * 256 + threadIdx.x;
    int lane = threadIdx.x & 63, wave = threadIdx.x >> 6;
    int cell = -1;
    float2 a = {0.f, 0.f};
    int mp = 0, sv = 0;
    if (e < E) {
        a = reinterpret_cast<const float2*>(attr)[e];
        cell = cell_of(a.x, a.y);
        int d = dst[e];
        int rank = atomicSub(&dhist[d], 1) - 1;      // count-1 .. 0 (permutation)
        mp = nof[d] + bbase[d >> 10] + rank;
        sv = src[e];
    }
    int myrank = 0;
    #pragma unroll
    for (int c = 0; c < 16; c++) {
        unsigned long long m = __ballot(cell == c);
        if (cell == c) myrank = __popcll(m & ((1ull << lane) - 1ull));
        if (lane == 0) wcnt[wave][c] = __popcll(m);
    }
    __syncthreads();
    if (threadIdx.x < 16) {
        int c = threadIdx.x;
        int t0 = wcnt[0][c], t1 = wcnt[1][c], t2 = wcnt[2][c], t3 = wcnt[3][c];
        int tot = t0 + t1 + t2 + t3;
        int g = tot ? atomicAdd(&cursor[c], tot) : 0;
        wbase[0][c] = g;
        wbase[1][c] = g + t0;
        wbase[2][c] = g + t0 + t1;
        wbase[3][c] = g + t0 + t1 + t2;
    }
    __syncthreads();
    if (e < E) {
        int slot = wbase[wave][cell] + myrank;
        emeta[slot] = make_int4(sv, mp, __float_as_int(a.x), __float_as_int(a.y));
    }
}

// ---------------------------------------------------------------------------
// layer_kernel: block-region merge of root GEMM + cell-bucketed edge GEMM.
//  [0, RG)   : rt[n,:] = x @ (root_hi+root_lo) + bias
//  [RG, ...) : one 512-edge CHUNK per block: stage Wcat[cell] in LDS once,
//              then loop 8 tiles (4 waves x 16 edges each):
//              G[t] = X[src] @ W[k_t(cell)]; msg[dstpos[e]] = bf16(sum_t w_t G[t])
// Stage+barrier amortized 8x vs R7; emeta = one 16B meta load per edge.
// ---------------------------------------------------------------------------
template<int KIN>
__global__ __launch_bounds__(256) void layer_kernel(
    const unsigned short* __restrict__ Xb,
    const unsigned short* __restrict__ pkr, float* __restrict__ rt,
    const float* __restrict__ bias, int N, int RG,
    const unsigned short* __restrict__ pkc, unsigned short* __restrict__ msg,
    const int4* __restrict__ emeta,
    const int* __restrict__ off_e, const int* __restrict__ off_b)
{
    constexpr int KCHr = KIN / 32;
    constexpr int KCH  = 4 * KCHr;
    __shared__ unsigned short Blds[4 * KCH * 512];

    const int lane = threadIdx.x & 63;
    const int wave = threadIdx.x >> 6;
    const int lrow = lane & 15, lch = lane >> 4;

    if (blockIdx.x < RG) {
        // ---- root GEMM ----
        const int mbase = blockIdx.x * 64 + wave * 16;
        short8 afrag[KCHr];
        {
            int row = mbase + lrow;
            if (row > N - 1) row = N - 1;
            const unsigned short* ap = Xb + (size_t)row * KIN + lch * 8;
            #pragma unroll
            for (int kc = 0; kc < KCHr; kc++)
                afrag[kc] = *reinterpret_cast<const short8*>(ap + kc * 32);
        }
        f32x4 acc[4];
        #pragma unroll
        for (int c = 0; c < 4; c++) acc[c] = (f32x4){0.f, 0.f, 0.f, 0.f};
        #pragma unroll
        for (int c = 0; c < 4; c++) {
            #pragma unroll
            for (int kc = 0; kc < KCHr; kc++) {
                short8 bh = *reinterpret_cast<const short8*>(pkr + ((size_t)(c * KCHr + kc) * 2    ) * 512 + lane * 8);
                short8 bl = *reinterpret_cast<const short8*>(pkr + ((size_t)(c * KCHr + kc) * 2 + 1) * 512 + lane * 8);
                acc[c] = __builtin_amdgcn_mfma_f32_16x16x32_bf16(afrag[kc], bh, acc[c], 0, 0, 0);
                acc[c] = __builtin_amdgcn_mfma_f32_16x16x32_bf16(afrag[kc], bl, acc[c], 0, 0, 0);
            }
        }
        #pragma unroll
        for (int c = 0; c < 4; c++) {
            int o = c * 16 + lrow;
            float bv = bias[o];
            #pragma unroll
            for (int r = 0; r < 4; r++) {
                int m = mbase + lch * 4 + r;
                if (m < N) rt[(size_t)m * 64 + o] = acc[c][r] + bv;
            }
        }
        return;
    }

    // ---- edge GEMM: one 512-edge chunk ----
    const int b = blockIdx.x - RG;
    if (b >= off_b[16]) return;
    int cell = 0;
    #pragma unroll
    for (int c = 1; c < 16; c++) cell += (b >= off_b[c]);
    const int chunk = b - off_b[cell];

    {   // stage Wcat[cell] -> LDS (linear, conflict-free) — ONCE per 512 edges
        const short8* sp = reinterpret_cast<const short8*>(pkc + (size_t)cell * (4 * KCH * 512));
        short8* dp = reinterpret_cast<short8*>(Blds);
        #pragma unroll
        for (int p = 0; p < (4 * KCH * 512 / 8) / 256; p++)
            dp[p * 256 + threadIdx.x] = sp[p * 256 + threadIdx.x];
    }
    __syncthreads();

    const int ebeg = off_e[cell];
    const int eend = off_e[cell + 1];
    const int base = ebeg + chunk * CHUNK;
    const float c0f = (float)(cell & 3), c1f = (float)(cell >> 2);

    for (int tt = 0; tt < 8; tt++) {
        const int tbase = base + (tt * 4 + wave) * 16;
        if (tbase >= eend) continue;            // wave-uniform tail skip
        const int eslot = tbase + lrow;
        const bool valid = eslot < eend;

        const int4 em = emeta[valid ? eslot : ebeg];
        const int s  = em.x;
        const int mp = valid ? em.y : -1;
        const float ax = __int_as_float(em.z);
        const float ay = __int_as_float(em.w);

        const float f0 = ax * 4.f - c0f;
        const float f1 = ay * 4.f - c1f;
        float w[4] = { (1.f - f0) * (1.f - f1), f0 * (1.f - f1),
                       (1.f - f0) * f1,         f0 * f1 };

        short8 xfrag[KCHr];
        {
            const unsigned short* xp = Xb + (size_t)s * KIN + lch * 8;
            #pragma unroll
            for (int kcr = 0; kcr < KCHr; kcr++)
                xfrag[kcr] = *reinterpret_cast<const short8*>(xp + kcr * 32);
        }

        // per-row basis weights + msg position (D layout: row = lch*4+r)
        float wr[4][4];
        int pv[4];
        #pragma unroll
        for (int r = 0; r < 4; r++) {
            int er = lch * 4 + r;
            #pragma unroll
            for (int t = 0; t < 4; t++) wr[t][r] = __shfl(w[t], er);
            pv[r] = __shfl(mp, er);
        }

        #pragma unroll
        for (int ch = 0; ch < 2; ch++) {
            f32x4 accT[4][2];  // [t][c2]
            #pragma unroll
            for (int t = 0; t < 4; t++)
                #pragma unroll
                for (int c2 = 0; c2 < 2; c2++)
                    accT[t][c2] = (f32x4){0.f, 0.f, 0.f, 0.f};

            #pragma unroll
            for (int t = 0; t < 4; t++) {
                #pragma unroll
                for (int kcr = 0; kcr < KCHr; kcr++) {
                    #pragma unroll
                    for (int c2 = 0; c2 < 2; c2++) {
                        int c = ch * 2 + c2;
                        short8 bf = *reinterpret_cast<const short8*>(
                            &Blds[(size_t)((c * KCH) + (t * KCHr + kcr)) * 512 + lane * 8]);
                        accT[t][c2] = __builtin_amdgcn_mfma_f32_16x16x32_bf16(xfrag[kcr], bf, accT[t][c2], 0, 0, 0);
                    }
                }
            }

            #pragma unroll
            for (int c2 = 0; c2 < 2; c2++) {
                const int o = (ch * 2 + c2) * 16 + lrow;
                #pragma unroll
                for (int r = 0; r < 4; r++) {
                    if (pv[r] >= 0) {
                        float m = wr[0][r] * accT[0][c2][r] + wr[1][r] * accT[1][c2][r]
                                + wr[2][r] * accT[2][c2][r] + wr[3][r] * accT[3][c2][r];
                        msg[(size_t)pv[r] * 64 + o] = f2bf(m);
                    }
                }
            }
        }
    }
}

// ---------------------------------------------------------------------------
// Segment-sum (dst-sorted bf16 msg rows contiguous per node) + root part.
// MODE 0: h = bf16(relu(rt + sum))      MODE 1: out = relu(rt+sum) @ fcw + fcb
// ---------------------------------------------------------------------------
template<int MODE>
__global__ __launch_bounds__(256) void segsum_kernel(
    const unsigned short* __restrict__ msg, const float* __restrict__ rt,
    const int* __restrict__ nof, const int* __restrict__ bbase,
    unsigned short* __restrict__ hout,
    const float* __restrict__ fcw, const float* __restrict__ fcb,
    float* __restrict__ out, int N)
{
    int n = blockIdx.x * 4 + (threadIdx.x >> 6);
    if (n >= N) return;
    int lane = threadIdx.x & 63;
    float acc = rt[(size_t)n * 64 + lane];
    int jb = nof[n]     + bbase[n >> 10];
    int je = nof[n + 1] + bbase[(n + 1) >> 10];
    int j = jb;
    for (; j + 3 < je; j += 4) {
        float a0 = bf2f(msg[(size_t)(j + 0) * 64 + lane]);
        float a1 = bf2f(msg[(size_t)(j + 1) * 64 + lane]);
        float a2 = bf2f(msg[(size_t)(j + 2) * 64 + lane]);
        float a3 = bf2f(msg[(size_t)(j + 3) * 64 + lane]);
        acc += a0; acc += a1; acc += a2; acc += a3;
    }
    for (; j < je; j++) acc += bf2f(msg[(size_t)j * 64 + lane]);
    acc = fmaxf(acc, 0.f);
    if (MODE == 0) {
        hout[(size_t)n * 64 + lane] = f2bf(acc);
    } else {
        float p0 = acc * fcw[lane * 3 + 0];
        float p1 = acc * fcw[lane * 3 + 1];
        float p2 = acc * fcw[lane * 3 + 2];
        #pragma unroll
        for (int off = 32; off; off >>= 1) {
            p0 += __shfl_xor(p0, off);
            p1 += __shfl_xor(p1, off);
            p2 += __shfl_xor(p2, off);
        }
        if (lane == 0) {
            out[(size_t)n * 3 + 0] = p0 + fcb[0];
            out[(size_t)n * 3 + 1] = p1 + fcb[1];
            out[(size_t)n * 3 + 2] = p2 + fcb[2];
        }
    }
}

// ---------------------------------------------------------------------------
extern "C" void kernel_launch(void* const* d_in, const int* in_sizes, int n_in,
                              void* d_out, int out_size, void* d_ws, size_t ws_size,
                              hipStream_t stream)
{
    const float* x     = (const float*)d_in[0];
    const int*   ei    = (const int*)  d_in[1];
    const float* attr  = (const float*)d_in[2];
    const float* W1    = (const float*)d_in[3];
    const float* root1 = (const float*)d_in[4];
    const float* b1    = (const float*)d_in[5];
    const float* W2    = (const float*)d_in[6];
    const float* root2 = (const float*)d_in[7];
    const float* b2    = (const float*)d_in[8];
    const float* fcw   = (const float*)d_in[9];
    const float* fcb   = (const float*)d_in[10];

    const int N = in_sizes[0] / 32;
    const int E = in_sizes[1] / 2;
    const int* srcp = ei;
    const int* dstp = ei + E;

    char* wsp = (char*)d_ws;
    auto alloc = [&](size_t bytes) -> char* {
        char* p = wsp;
        wsp += (bytes + 255) & ~(size_t)255;
        return p;
    };
    const int NB = (N + 1 + 1023) / 1024;   // scanA blocks

    float*          rt       = (float*)alloc((size_t)N * 64 * 4);
    unsigned short* xb       = (unsigned short*)alloc((size_t)N * 32 * 2);
    unsigned short* h1b      = (unsigned short*)alloc((size_t)N * 64 * 2);
    unsigned short* pkr1     = (unsigned short*)alloc((size_t)4 * 1 * 2 * 512 * 2);
    unsigned short* pkr2     = (unsigned short*)alloc((size_t)4 * 2 * 2 * 512 * 2);
    unsigned short* pkc1     = (unsigned short*)alloc((size_t)16 * 4 * 4 * 512 * 2);
    unsigned short* pkc2     = (unsigned short*)alloc((size_t)16 * 4 * 8 * 512 * 2);
    int4*           emeta    = (int4*)alloc((size_t)E * 16);
    int*            nof      = (int*)alloc((size_t)(N + 1) * 4);
    int*            bsum     = (int*)alloc((size_t)NB * 4);
    int*            bbase    = (int*)alloc((size_t)NB * 4);
    int*            off_e    = (int*)alloc(17 * 4);
    int*            off_b    = (int*)alloc(17 * 4);
    int*            cursor   = (int*)alloc(16 * 4);
    // zeroed region: hist16 | dhist[N+1]
    int*            zbase    = (int*)alloc((size_t)(16 + N + 1) * 4);
    int*            hist     = zbase;
    int*            dhist    = zbase + 16;
    unsigned short* msg      = (unsigned short*)alloc((size_t)E * 64 * 2);

    const int ZN = 16 + N + 1;
    zero_kernel<<<(ZN + 255) / 256, 256, 0, stream>>>(zbase, ZN);

    const int EB = (E + 255) / 256;
    const int CB = (N * 8 + 255) / 256;              // float4 convert blocks
    const int prep_grid = EB + 512 + 1024 + 8 + 16 + CB;

    prep_kernel<<<prep_grid, 256, 0, stream>>>(attr, dstp, hist, dhist, E,
                                               W1, W2, root1, root2,
                                               pkc1, pkc2, pkr1, pkr2,
                                               x, xb, N * 8, EB);
    scanA_kernel<<<NB, 1024, 0, stream>>>(dhist, nof, bsum, N + 1);
    scan_small_kernel<<<1, 64, 0, stream>>>(hist, off_e, off_b, cursor, bsum, bbase, NB);
    scatter_kernel<<<EB, 256, 0, stream>>>(attr, srcp, dstp, nof, bbase, emeta, cursor, dhist, E);

    const int RG = (N + 63) / 64;
    const int lgrid = RG + (E + CHUNK - 1) / CHUNK + 16;   // upper bound incl. per-cell ceil
    const int sgrid = (N + 3) / 4;

    layer_kernel<32><<<lgrid, 256, 0, stream>>>(xb, pkr1, rt, b1, N, RG,
                                                pkc1, msg, emeta, off_e, off_b);
    segsum_kernel<0><<<sgrid, 256, 0, stream>>>(msg, rt, nof, bbase, h1b, fcw, fcb, (float*)d_out, N);

    layer_kernel<64><<<lgrid, 256, 0, stream>>>(h1b, pkr2, rt, b2, N, RG,
                                                pkc2, msg, emeta, off_e, off_b);
    segsum_kernel<1><<<sgrid, 256, 0, stream>>>(msg, rt, nof, bbase, nullptr, fcw, fcb, (float*)d_out, N);
}